// Round 11
// baseline (1155.812 us; speedup 1.0000x reference)
//
#include <hip/hip_runtime.h>
#include <math.h>

#define LYRS 6
#define BATCH 16
#define DIM 1024
#define NH 16
#define HDIM 64
#define FFNDIM 4096
#define VOCAB 32000
#define NCACHE 512
#define SRCLEN 512
#define SCALE 0.125f
#define EMB_SCALE 32.0f
#define BD (BATCH * DIM)
#define BF (BATCH * FFNDIM)
#define BV (BATCH * VOCAB)

__device__ __forceinline__ float wave_reduce_sum(float v){
#pragma unroll
  for (int off = 32; off; off >>= 1) v += __shfl_xor(v, off, 64);
  return v;
}
__device__ __forceinline__ float wave_reduce_max(float v){
#pragma unroll
  for (int off = 32; off; off >>= 1) v = fmaxf(v, __shfl_xor(v, off, 64));
  return v;
}
__device__ __forceinline__ float4 silu4(float4 v){
  v.x = v.x / (1.f + __expf(-v.x));
  v.y = v.y / (1.f + __expf(-v.y));
  v.z = v.z / (1.f + __expf(-v.z));
  v.w = v.w / (1.f + __expf(-v.w));
  return v;
}

// ---- coherent (agent-scope, L2-bypass) accessors for intra-kernel sharing ----
__device__ __forceinline__ float4 gld4(const float* p){
  unsigned long long a = __hip_atomic_load((const unsigned long long*)p,
      __ATOMIC_RELAXED, __HIP_MEMORY_SCOPE_AGENT);
  unsigned long long b = __hip_atomic_load((const unsigned long long*)(p + 2),
      __ATOMIC_RELAXED, __HIP_MEMORY_SCOPE_AGENT);
  float4 r;
  r.x = __uint_as_float((unsigned)a); r.y = __uint_as_float((unsigned)(a >> 32));
  r.z = __uint_as_float((unsigned)b); r.w = __uint_as_float((unsigned)(b >> 32));
  return r;
}
__device__ __forceinline__ void gst4(float* p, float4 v){
  unsigned long long a = (unsigned long long)__float_as_uint(v.x) |
                         ((unsigned long long)__float_as_uint(v.y) << 32);
  unsigned long long b = (unsigned long long)__float_as_uint(v.z) |
                         ((unsigned long long)__float_as_uint(v.w) << 32);
  __hip_atomic_store((unsigned long long*)p, a, __ATOMIC_RELAXED,
                     __HIP_MEMORY_SCOPE_AGENT);
  __hip_atomic_store((unsigned long long*)(p + 2), b, __ATOMIC_RELAXED,
                     __HIP_MEMORY_SCOPE_AGENT);
}

// ---------------------------------------------------------------------------
// Staging A: plain (optional NZ partial-slab fold + k-bias + SiLU).
// ---------------------------------------------------------------------------
template<int KPB, int NZ, bool SILU>
__device__ __forceinline__ void plain_stage(float (*As)[KPB],
    const float* __restrict__ Asrc, int a_rs, int pz,
    const float* __restrict__ abias, int k0){
  const int tid = threadIdx.x;
  const int m = tid >> 4, q0 = (tid & 15) * 4;
#pragma unroll
  for (int qq = 0; qq < KPB / 64; ++qq){
    const int q = q0 + qq * 64;
    const int gk = k0 + q;
    float4 v;
    if (NZ == 0){
      v = *(const float4*)(Asrc + (size_t)m * a_rs + gk);
    } else {
      if (abias) v = *(const float4*)(abias + gk);
      else { v.x = 0.f; v.y = 0.f; v.z = 0.f; v.w = 0.f; }
#pragma unroll
      for (int z = 0; z < NZ; ++z){
        float4 pv = *(const float4*)(Asrc + (size_t)z * pz + (size_t)m * a_rs + gk);
        v.x += pv.x; v.y += pv.y; v.z += pv.z; v.w += pv.w;
      }
    }
    if (SILU) v = silu4(v);
    *(float4*)(&As[m][q]) = v;
  }
  __syncthreads();
}

// ---------------------------------------------------------------------------
// GEMV W-stream loop (double-buffered), slab store.
// ---------------------------------------------------------------------------
template<int KPB>
__device__ __forceinline__ void gemv_w_loop(float (*As)[KPB],
    const float* __restrict__ W, int w_rs, float* __restrict__ Cz,
    int c_rs, int n0, int k0){
  const int tid = threadIdx.x, lane = tid & 63;
  const int m0 = (tid >> 6) * 4;
  const float* Wrow = W + (size_t)(n0 + lane) * w_rs + k0;
  float acc0 = 0.f, acc1 = 0.f, acc2 = 0.f, acc3 = 0.f;
  constexpr int CHUNKS = KPB / 64;
  float4 wb[2][16];
#pragma unroll
  for (int c = 0; c < 16; ++c) wb[0][c] = *(const float4*)(Wrow + c * 4);
#pragma unroll
  for (int ch = 0; ch < CHUNKS; ++ch){
    const int cur = ch & 1;
    if (ch + 1 < CHUNKS){
#pragma unroll
      for (int c = 0; c < 16; ++c)
        wb[cur ^ 1][c] = *(const float4*)(Wrow + (ch + 1) * 64 + c * 4);
    }
#pragma unroll
    for (int c = 0; c < 16; ++c){
      float4 wv = wb[cur][c];
      const int q = ch * 64 + c * 4;
      float4 a0 = *(const float4*)(&As[m0 + 0][q]);
      float4 a1 = *(const float4*)(&As[m0 + 1][q]);
      float4 a2 = *(const float4*)(&As[m0 + 2][q]);
      float4 a3 = *(const float4*)(&As[m0 + 3][q]);
      acc0 = fmaf(wv.x, a0.x, acc0); acc0 = fmaf(wv.y, a0.y, acc0);
      acc0 = fmaf(wv.z, a0.z, acc0); acc0 = fmaf(wv.w, a0.w, acc0);
      acc1 = fmaf(wv.x, a1.x, acc1); acc1 = fmaf(wv.y, a1.y, acc1);
      acc1 = fmaf(wv.z, a1.z, acc1); acc1 = fmaf(wv.w, a1.w, acc1);
      acc2 = fmaf(wv.x, a2.x, acc2); acc2 = fmaf(wv.y, a2.y, acc2);
      acc2 = fmaf(wv.z, a2.z, acc2); acc2 = fmaf(wv.w, a2.w, acc2);
      acc3 = fmaf(wv.x, a3.x, acc3); acc3 = fmaf(wv.y, a3.y, acc3);
      acc3 = fmaf(wv.z, a3.z, acc3); acc3 = fmaf(wv.w, a3.w, acc3);
    }
  }
  Cz[(size_t)(m0 + 0) * c_rs + n0 + lane] = acc0;
  Cz[(size_t)(m0 + 1) * c_rs + n0 + lane] = acc1;
  Cz[(size_t)(m0 + 2) * c_rs + n0 + lane] = acc2;
  Cz[(size_t)(m0 + 3) * c_rs + n0 + lane] = acc3;
}

template<int KPB, int NZ, bool SILU>
__global__ __launch_bounds__(256) void k_gemv_ms(
    const float* __restrict__ A, int a_rs, int a_bs, int pz,
    const float* __restrict__ abias,
    const float* __restrict__ W, int w_rs, int w_bs,
    float* __restrict__ C, int c_rs, int c_bs, int c_zs){
  __shared__ float As[16][KPB];
  const int bb = blockIdx.y;
  plain_stage<KPB, NZ, SILU>(As, A + (size_t)bb * a_bs, a_rs, pz, abias,
                             blockIdx.z * KPB);
  gemv_w_loop<KPB>(As, W + (size_t)bb * w_bs, w_rs,
      C + (size_t)blockIdx.z * c_zs + (size_t)bb * c_bs, c_rs,
      blockIdx.x * 64, blockIdx.z * KPB);
}

// Layer-0 QKV with embed fused: staging computes h = de*EMB_SCALE + pe[cl]
// redundantly; blocks (bx==0,by==0) materialize h into hout for later use.
__global__ __launch_bounds__(256) void k_qkv0(
    const float* __restrict__ de, const float* __restrict__ pe,
    const int* __restrict__ cl,
    const float* __restrict__ W0, const float* __restrict__ W1,
    const float* __restrict__ W2,
    float* __restrict__ hout, float* __restrict__ C){
  __shared__ float As[16][256];
  const int bx = blockIdx.x, by = blockIdx.y, bz = blockIdx.z;
  const int tid = threadIdx.x;
  const int k0 = bz * 256;
  const int c = cl[0];
  {
    const int m = tid >> 4, q0 = (tid & 15) * 4;
#pragma unroll
    for (int qq = 0; qq < 4; ++qq){
      const int q = q0 + qq * 64, gk = k0 + q;
      float4 a = *(const float4*)(de + (size_t)m * DIM + gk);
      float4 p = *(const float4*)(pe + (size_t)c * DIM + gk);
      float4 v;
      v.x = a.x * EMB_SCALE + p.x; v.y = a.y * EMB_SCALE + p.y;
      v.z = a.z * EMB_SCALE + p.z; v.w = a.w * EMB_SCALE + p.w;
      *(float4*)(&As[m][q]) = v;
      if (bx == 0 && by == 0)
        *(float4*)(hout + (size_t)m * DIM + gk) = v;
    }
  }
  __syncthreads();
  const float* W = (by == 0) ? W0 : ((by == 1) ? W1 : W2);
  gemv_w_loop<256>(As, W, DIM, C + (size_t)(by * 4 + bz) * BD, DIM,
                   bx * 64, k0);
}

// LN producer: this block computes LayerNorm of row b (res + sum_z P + obias),
// writes it to hout (agent-coherent), releases flag[b] = gen.
template<int NZ>
__device__ void ln_row(int b, const float* __restrict__ res,
    const float* __restrict__ P, int pzs, const float* __restrict__ obias,
    const float* __restrict__ lnw, const float* __restrict__ lnb,
    float* __restrict__ hout, int* __restrict__ flags, int gen){
  __shared__ float r1[4], r2[4];
  const int tid = threadIdx.x, wave = tid >> 6, lane = tid & 63;
  float4 x = ((const float4*)(res + (size_t)b * DIM))[tid];
  float4 ob = ((const float4*)obias)[tid];
  x.x += ob.x; x.y += ob.y; x.z += ob.z; x.w += ob.w;
#pragma unroll
  for (int z = 0; z < NZ; ++z){
    float4 p = ((const float4*)(P + (size_t)z * pzs + (size_t)b * DIM))[tid];
    x.x += p.x; x.y += p.y; x.z += p.z; x.w += p.w;
  }
  float s = x.x + x.y + x.z + x.w;
  float sq = x.x * x.x + x.y * x.y + x.z * x.z + x.w * x.w;
  s = wave_reduce_sum(s); sq = wave_reduce_sum(sq);
  if (lane == 0){ r1[wave] = s; r2[wave] = sq; }
  __syncthreads();
  float ts = r1[0] + r1[1] + r1[2] + r1[3];
  float tq = r2[0] + r2[1] + r2[2] + r2[3];
  float mean = ts * (1.f / DIM);
  float rstd = rsqrtf(tq * (1.f / DIM) - mean * mean + 1e-5f);
  float4 wv = ((const float4*)lnw)[tid], bv = ((const float4*)lnb)[tid];
  float4 o;
  o.x = (x.x - mean) * rstd * wv.x + bv.x;
  o.y = (x.y - mean) * rstd * wv.y + bv.y;
  o.z = (x.z - mean) * rstd * wv.z + bv.z;
  o.w = (x.w - mean) * rstd * wv.w + bv.w;
  gst4(hout + (size_t)b * DIM + tid * 4, o);
  __syncthreads();   // drains vmcnt: row stores complete before release
  if (tid == 0)
    __hip_atomic_store(&flags[b * 32], gen, __ATOMIC_RELEASE,
                       __HIP_MEMORY_SCOPE_AGENT);
}

__device__ __forceinline__ void flag_wait16(const int* __restrict__ flags,
                                            int gen){
  if (threadIdx.x < 16){
    while (__hip_atomic_load(&flags[threadIdx.x * 32], __ATOMIC_ACQUIRE,
                             __HIP_MEMORY_SCOPE_AGENT) < gen)
      __builtin_amdgcn_s_sleep(2);
  }
  __syncthreads();
}

// ---------------------------------------------------------------------------
// GEMV with intra-kernel fused LayerNorm. 16 designated blocks (by==0,bz==0,
// bx<16) each produce one LN row into hout + release a flag; all blocks
// prefetch W chunk-0 (independent of LN), wait on the 16 flags, stage the LN
// output via coherent loads, and run the W-stream loop. Grid must be <=256
// blocks (co-resident at 1 block/CU -> spin is deadlock-free).
// ---------------------------------------------------------------------------
template<int KPB, int NZ>
__global__ __launch_bounds__(256) void k_gemv_lnf(
    const float* __restrict__ res, const float* __restrict__ P, int pzs,
    const float* __restrict__ obias, const float* __restrict__ lnw,
    const float* __restrict__ lnb,
    const float* __restrict__ W0, const float* __restrict__ W1,
    const float* __restrict__ W2,
    float* __restrict__ hout, int* __restrict__ flags, int gen,
    float* __restrict__ C, int c_rs, int slab_elems){
  __shared__ float As[16][KPB];
  const int bx = blockIdx.x, by = blockIdx.y, bz = blockIdx.z;
  const int tid = threadIdx.x, lane = tid & 63;
  const int k0 = bz * KPB, n0 = bx * 64;
  const float* W = (by == 0) ? W0 : ((by == 1) ? W1 : W2);
  const float* Wrow = W + (size_t)(n0 + lane) * DIM + k0;
  constexpr int CHUNKS = KPB / 64;
  float4 wb[2][16];
#pragma unroll
  for (int c = 0; c < 16; ++c) wb[0][c] = *(const float4*)(Wrow + c * 4);
  if (by == 0 && bz == 0 && bx < 16)
    ln_row<NZ>(bx, res, P, pzs, obias, lnw, lnb, hout, flags, gen);
  flag_wait16(flags, gen);
  {
    const int m = tid >> 4, q0 = (tid & 15) * 4;
#pragma unroll
    for (int qq = 0; qq < KPB / 64; ++qq){
      const int q = q0 + qq * 64;
      float4 v = gld4(hout + (size_t)m * DIM + k0 + q);
      *(float4*)(&As[m][q]) = v;
    }
  }
  __syncthreads();
  const int m0 = (tid >> 6) * 4;
  float acc0 = 0.f, acc1 = 0.f, acc2 = 0.f, acc3 = 0.f;
#pragma unroll
  for (int ch = 0; ch < CHUNKS; ++ch){
    const int cur = ch & 1;
    if (ch + 1 < CHUNKS){
#pragma unroll
      for (int c = 0; c < 16; ++c)
        wb[cur ^ 1][c] = *(const float4*)(Wrow + (ch + 1) * 64 + c * 4);
    }
#pragma unroll
    for (int c = 0; c < 16; ++c){
      float4 wv = wb[cur][c];
      const int q = ch * 64 + c * 4;
      float4 a0 = *(const float4*)(&As[m0 + 0][q]);
      float4 a1 = *(const float4*)(&As[m0 + 1][q]);
      float4 a2 = *(const float4*)(&As[m0 + 2][q]);
      float4 a3 = *(const float4*)(&As[m0 + 3][q]);
      acc0 = fmaf(wv.x, a0.x, acc0); acc0 = fmaf(wv.y, a0.y, acc0);
      acc0 = fmaf(wv.z, a0.z, acc0); acc0 = fmaf(wv.w, a0.w, acc0);
      acc1 = fmaf(wv.x, a1.x, acc1); acc1 = fmaf(wv.y, a1.y, acc1);
      acc1 = fmaf(wv.z, a1.z, acc1); acc1 = fmaf(wv.w, a1.w, acc1);
      acc2 = fmaf(wv.x, a2.x, acc2); acc2 = fmaf(wv.y, a2.y, acc2);
      acc2 = fmaf(wv.z, a2.z, acc2); acc2 = fmaf(wv.w, a2.w, acc2);
      acc3 = fmaf(wv.x, a3.x, acc3); acc3 = fmaf(wv.y, a3.y, acc3);
      acc3 = fmaf(wv.z, a3.z, acc3); acc3 = fmaf(wv.w, a3.w, acc3);
    }
  }
  float* Cz = C + (size_t)(by * gridDim.z + bz) * slab_elems;
  Cz[(size_t)(m0 + 0) * c_rs + n0 + lane] = acc0;
  Cz[(size_t)(m0 + 1) * c_rs + n0 + lane] = acc1;
  Cz[(size_t)(m0 + 2) * c_rs + n0 + lane] = acc2;
  Cz[(size_t)(m0 + 3) * c_rs + n0 + lane] = acc3;
}

// Self-attention per (b,h). Folds the 4 QKV k-split partials (+bias),
// writes new k/v to d_out, attends over 513 keys.
__global__ __launch_bounds__(512) void k_self_attn(
    const float* __restrict__ Pqkv, const float* __restrict__ qb_,
    const float* __restrict__ kb_, const float* __restrict__ vb_,
    const float* __restrict__ pk, const float* __restrict__ pv,
    float* __restrict__ satt, float* __restrict__ out_k,
    float* __restrict__ out_v){
  __shared__ float qs[64], ks[64], vs[64];
  __shared__ float sc[513];
  __shared__ float red1[8], red2[8];
  __shared__ float o8[8][64];
  const int bh = blockIdx.x, b = bh >> 4, h = bh & 15;
  const int tid = threadIdx.x, w = tid >> 6, lane = tid & 63;
  const int hd = h * HDIM + lane;
  if (w < 3){
    const float* Pz = Pqkv + (size_t)w * (4 * BD);
    const float* bias = (w == 0) ? qb_ : ((w == 1) ? kb_ : vb_);
    float v = bias[hd];
#pragma unroll
    for (int z = 0; z < 4; ++z)
      v += Pz[(size_t)z * BD + b * DIM + hd];
    if (w == 0) qs[lane] = v * SCALE;
    else if (w == 1){ ks[lane] = v; out_k[b * DIM + hd] = v; }
    else { vs[lane] = v; out_v[b * DIM + hd] = v; }
  }
  __syncthreads();
  const int jj = lane >> 4, c = lane & 15;
  float4 q4 = *(const float4*)(&qs[c * 4]);
  const float* kbase = pk + (size_t)b * NCACHE * DIM + h * HDIM + c * 4;
  {
    float4 nk = *(const float4*)(kbase + (size_t)(w * 4 + jj) * DIM);
    for (int it = 0; it < 16; ++it){
      int j = it * 32 + w * 4 + jj;
      float4 K4 = nk;
      if (it < 15) nk = *(const float4*)(kbase + (size_t)(j + 32) * DIM);
      float r = q4.x * K4.x;
      r = fmaf(q4.y, K4.y, r); r = fmaf(q4.z, K4.z, r); r = fmaf(q4.w, K4.w, r);
      r += __shfl_xor(r, 1, 64); r += __shfl_xor(r, 2, 64);
      r += __shfl_xor(r, 4, 64); r += __shfl_xor(r, 8, 64);
      if (c == 0) sc[j] = r;
    }
  }
  if (w == 0 && lane < 16){
    float4 k4 = *(const float4*)(&ks[lane * 4]);
    float r = q4.x * k4.x;
    r = fmaf(q4.y, k4.y, r); r = fmaf(q4.z, k4.z, r); r = fmaf(q4.w, k4.w, r);
    r += __shfl_xor(r, 1, 64); r += __shfl_xor(r, 2, 64);
    r += __shfl_xor(r, 4, 64); r += __shfl_xor(r, 8, 64);
    if (lane == 0) sc[512] = r;
  }
  __syncthreads();
  float lm = -1e30f;
  for (int j2 = tid; j2 < 513; j2 += 512) lm = fmaxf(lm, sc[j2]);
  lm = wave_reduce_max(lm);
  if (lane == 0) red1[w] = lm;
  __syncthreads();
  float bm = red1[0];
#pragma unroll
  for (int ww = 1; ww < 8; ++ww) bm = fmaxf(bm, red1[ww]);
  float ls = 0.f;
  for (int j2 = tid; j2 < 513; j2 += 512){
    float e = __expf(sc[j2] - bm);
    sc[j2] = e;
    ls += e;
  }
  ls = wave_reduce_sum(ls);
  if (lane == 0) red2[w] = ls;
  __syncthreads();
  float tot = 0.f;
#pragma unroll
  for (int ww = 0; ww < 8; ++ww) tot += red2[ww];
  float inv = 1.f / tot;
  const float* vbase = pv + (size_t)b * NCACHE * DIM + h * HDIM + c * 4;
  float4 acc; acc.x = 0.f; acc.y = 0.f; acc.z = 0.f; acc.w = 0.f;
  {
    float4 nv = *(const float4*)(vbase + (size_t)(w * 4 + jj) * DIM);
    for (int it = 0; it < 16; ++it){
      int j = it * 32 + w * 4 + jj;
      float4 V4 = nv;
      if (it < 15) nv = *(const float4*)(vbase + (size_t)(j + 32) * DIM);
      float pj = sc[j];
      acc.x = fmaf(pj, V4.x, acc.x); acc.y = fmaf(pj, V4.y, acc.y);
      acc.z = fmaf(pj, V4.z, acc.z); acc.w = fmaf(pj, V4.w, acc.w);
    }
  }
  if (w == 0 && lane < 16){
    float p512 = sc[512];
    float4 v4 = *(const float4*)(&vs[lane * 4]);
    acc.x = fmaf(p512, v4.x, acc.x); acc.y = fmaf(p512, v4.y, acc.y);
    acc.z = fmaf(p512, v4.z, acc.z); acc.w = fmaf(p512, v4.w, acc.w);
  }
  acc.x += __shfl_xor(acc.x, 16, 64); acc.x += __shfl_xor(acc.x, 32, 64);
  acc.y += __shfl_xor(acc.y, 16, 64); acc.y += __shfl_xor(acc.y, 32, 64);
  acc.z += __shfl_xor(acc.z, 16, 64); acc.z += __shfl_xor(acc.z, 32, 64);
  acc.w += __shfl_xor(acc.w, 16, 64); acc.w += __shfl_xor(acc.w, 32, 64);
  if (lane < 16){
    o8[w][lane * 4 + 0] = acc.x; o8[w][lane * 4 + 1] = acc.y;
    o8[w][lane * 4 + 2] = acc.z; o8[w][lane * 4 + 3] = acc.w;
  }
  __syncthreads();
  if (tid < 64){
    float s2 = 0.f;
#pragma unroll
    for (int ww = 0; ww < 8; ++ww) s2 += o8[ww][tid];
    satt[b * DIM + h * HDIM + tid] = s2 * inv;
  }
}

// h = LayerNorm(res + sum_z P[z] + obias) * w + b  (final ln3 only)
template<int NZ>
__global__ __launch_bounds__(256) void k_add_ln_pz(
    const float* __restrict__ res, const float* __restrict__ P, int zs,
    const float* __restrict__ obias, const float* __restrict__ w,
    const float* __restrict__ bln, float* __restrict__ outh){
  __shared__ float r1[4], r2[4];
  int b = blockIdx.x, tid = threadIdx.x, wave = tid >> 6, lane = tid & 63;
  float4 rv = ((const float4*)(res + (size_t)b * DIM))[tid];
  float4 ob = ((const float4*)obias)[tid];
  float v0 = rv.x + ob.x, v1 = rv.y + ob.y, v2 = rv.z + ob.z, v3 = rv.w + ob.w;
#pragma unroll
  for (int z = 0; z < NZ; ++z){
    float4 pz = ((const float4*)(P + (size_t)z * zs + (size_t)b * DIM))[tid];
    v0 += pz.x; v1 += pz.y; v2 += pz.z; v3 += pz.w;
  }
  float s = v0 + v1 + v2 + v3;
  float sq = v0 * v0 + v1 * v1 + v2 * v2 + v3 * v3;
  s = wave_reduce_sum(s); sq = wave_reduce_sum(sq);
  if (lane == 0){ r1[wave] = s; r2[wave] = sq; }
  __syncthreads();
  float ts = r1[0] + r1[1] + r1[2] + r1[3];
  float tq = r2[0] + r2[1] + r2[2] + r2[3];
  float mean = ts * (1.f / DIM);
  float var = tq * (1.f / DIM) - mean * mean;
  float rstd = rsqrtf(var + 1e-5f);
  float4 wv = ((const float4*)w)[tid], bv = ((const float4*)bln)[tid];
  float4 o;
  o.x = (v0 - mean) * rstd * wv.x + bv.x;
  o.y = (v1 - mean) * rstd * wv.y + bv.y;
  o.z = (v2 - mean) * rstd * wv.z + bv.z;
  o.w = (v3 - mean) * rstd * wv.w + bv.w;
  ((float4*)(outh + (size_t)b * DIM))[tid] = o;
}

// g[b][h][c] = sum_d qv[b][hd] * kw[hd][c], qv = (sum8 Pcq + caqb)*SCALE
__global__ __launch_bounds__(256) void k_gmat2(
    const float* __restrict__ Pcq, const float* __restrict__ caqb,
    const float* __restrict__ kw, float* __restrict__ g){
  __shared__ float qsT[64][16];   // [d][b]
  __shared__ float Ps[4][16][64];
  const int h = blockIdx.y, c0 = blockIdx.x * 64;
  const int tid = threadIdx.x, lane = tid & 63, wave = tid >> 6;
  {
    const int b = tid >> 4, q0 = (tid & 15) * 4;
    float4 v = *(const float4*)(caqb + h * HDIM + q0);
#pragma unroll
    for (int z = 0; z < 8; ++z){
      float4 pv = *(const float4*)(Pcq + (size_t)z * BD +
                                   (size_t)b * DIM + h * HDIM + q0);
      v.x += pv.x; v.y += pv.y; v.z += pv.z; v.w += pv.w;
    }
    qsT[q0 + 0][b] = v.x * SCALE; qsT[q0 + 1][b] = v.y * SCALE;
    qsT[q0 + 2][b] = v.z * SCALE; qsT[q0 + 3][b] = v.w * SCALE;
  }
  __syncthreads();
  float wv[16];
#pragma unroll
  for (int dd = 0; dd < 16; ++dd)
    wv[dd] = kw[(size_t)(h * HDIM + wave * 16 + dd) * DIM + c0 + lane];
  float acc[16];
#pragma unroll
  for (int m = 0; m < 16; ++m) acc[m] = 0.f;
#pragma unroll
  for (int dd = 0; dd < 16; ++dd){
    const int d = wave * 16 + dd;
    float4 a0 = *(const float4*)(&qsT[d][0]);
    float4 a1 = *(const float4*)(&qsT[d][4]);
    float4 a2 = *(const float4*)(&qsT[d][8]);
    float4 a3 = *(const float4*)(&qsT[d][12]);
    float wd = wv[dd];
    acc[0] = fmaf(wd, a0.x, acc[0]);  acc[1] = fmaf(wd, a0.y, acc[1]);
    acc[2] = fmaf(wd, a0.z, acc[2]);  acc[3] = fmaf(wd, a0.w, acc[3]);
    acc[4] = fmaf(wd, a1.x, acc[4]);  acc[5] = fmaf(wd, a1.y, acc[5]);
    acc[6] = fmaf(wd, a1.z, acc[6]);  acc[7] = fmaf(wd, a1.w, acc[7]);
    acc[8] = fmaf(wd, a2.x, acc[8]);  acc[9] = fmaf(wd, a2.y, acc[9]);
    acc[10] = fmaf(wd, a2.z, acc[10]); acc[11] = fmaf(wd, a2.w, acc[11]);
    acc[12] = fmaf(wd, a3.x, acc[12]); acc[13] = fmaf(wd, a3.y, acc[13]);
    acc[14] = fmaf(wd, a3.z, acc[14]); acc[15] = fmaf(wd, a3.w, acc[15]);
  }
#pragma unroll
  for (int m = 0; m < 16; ++m) Ps[wave][m][lane] = acc[m];
  __syncthreads();
  const int nl = tid & 63, mg = (tid >> 6) * 4;
#pragma unroll
  for (int mm = 0; mm < 4; ++mm){
    int m = mg + mm;
    float r = Ps[0][m][nl] + Ps[1][m][nl] + Ps[2][m][nl] + Ps[3][m][nl];
    g[((size_t)m * NH + h) * DIM + c0 + nl] = r;
  }
}

// ctx with INLINE softmax over sum of 2 score slabs; then ctx = p . enc
__global__ __launch_bounds__(256) void k_ctx_sm(
    const float* __restrict__ s2b, const float* __restrict__ enc,
    float* __restrict__ ctx){
  __shared__ float pT[SRCLEN][16];
  __shared__ float Ps[4][16][64];
  const int b = blockIdx.y, c0 = blockIdx.x * 64;
  const int tid = threadIdx.x, lane = tid & 63, wave = tid >> 6;
  {
    const int h = tid >> 4, jp = (tid & 15) * 4;
    const size_t row = ((size_t)b * NH + h) * SRCLEN;
    float4 val[8];
    float vmax = -1e30f;
#pragma unroll
    for (int t = 0; t < 8; ++t){
      const int j = jp + t * 64;
      float4 v = *(const float4*)(s2b + row + j);
      float4 v2 = *(const float4*)(s2b + (size_t)(BATCH * NH * SRCLEN) + row + j);
      v.x += v2.x; v.y += v2.y; v.z += v2.z; v.w += v2.w;
      val[t] = v;
      vmax = fmaxf(vmax, fmaxf(fmaxf(v.x, v.y), fmaxf(v.z, v.w)));
    }
#pragma unroll
    for (int o = 1; o <= 8; o <<= 1) vmax = fmaxf(vmax, __shfl_xor(vmax, o, 64));
    float lsum = 0.f;
#pragma unroll
    for (int t = 0; t < 8; ++t){
      val[t].x = __expf(val[t].x - vmax); val[t].y = __expf(val[t].y - vmax);
      val[t].z = __expf(val[t].z - vmax); val[t].w = __expf(val[t].w - vmax);
      lsum += val[t].x + val[t].y + val[t].z + val[t].w;
    }
#pragma unroll
    for (int o = 1; o <= 8; o <<= 1) lsum += __shfl_xor(lsum, o, 64);
    float inv = 1.f / lsum;
#pragma unroll
    for (int t = 0; t < 8; ++t){
      const int j = jp + t * 64;
      pT[j + 0][h] = val[t].x * inv; pT[j + 1][h] = val[t].y * inv;
      pT[j + 2][h] = val[t].z * inv; pT[j + 3][h] = val[t].w * inv;
    }
  }
  __syncthreads();
  const float* ep = enc + (size_t)b * SRCLEN * DIM + c0 + lane;
  const int jb = wave * 128;
  float acc[16];
#pragma unroll
  for (int m = 0; m < 16; ++m) acc[m] = 0.f;
  float cur[8], nxt[8];
#pragma unroll
  for (int i = 0; i < 8; ++i) cur[i] = ep[(size_t)(jb + i) * DIM];
#pragma unroll
  for (int t = 0; t < 16; ++t){
    if (t < 15){
#pragma unroll
      for (int i = 0; i < 8; ++i)
        nxt[i] = ep[(size_t)(jb + (t + 1) * 8 + i) * DIM];
    }
#pragma unroll
    for (int i = 0; i < 8; ++i){
      const int j = jb + t * 8 + i;
      float4 p0 = *(const float4*)(&pT[j][0]);
      float4 p1 = *(const float4*)(&pT[j][4]);
      float4 p2 = *(const float4*)(&pT[j][8]);
      float4 p3 = *(const float4*)(&pT[j][12]);
      float ev = cur[i];
      acc[0] = fmaf(p0.x, ev, acc[0]);  acc[1] = fmaf(p0.y, ev, acc[1]);
      acc[2] = fmaf(p0.z, ev, acc[2]);  acc[3] = fmaf(p0.w, ev, acc[3]);
      acc[4] = fmaf(p1.x, ev, acc[4]);  acc[5] = fmaf(p1.y, ev, acc[5]);
      acc[6] = fmaf(p1.z, ev, acc[6]);  acc[7] = fmaf(p1.w, ev, acc[7]);
      acc[8] = fmaf(p2.x, ev, acc[8]);  acc[9] = fmaf(p2.y, ev, acc[9]);
      acc[10] = fmaf(p2.z, ev, acc[10]); acc[11] = fmaf(p2.w, ev, acc[11]);
      acc[12] = fmaf(p3.x, ev, acc[12]); acc[13] = fmaf(p3.y, ev, acc[13]);
      acc[14] = fmaf(p3.z, ev, acc[14]); acc[15] = fmaf(p3.w, ev, acc[15]);
    }
#pragma unroll
    for (int i = 0; i < 8; ++i) cur[i] = nxt[i];
  }
#pragma unroll
  for (int m = 0; m < 16; ++m) Ps[wave][m][lane] = acc[m];
  __syncthreads();
  const int nl = tid & 63, mg = (tid >> 6) * 4;
#pragma unroll
  for (int mm = 0; mm < 4; ++mm){
    int m = mg + mm;
    float r = Ps[0][m][nl] + Ps[1][m][nl] + Ps[2][m][nl] + Ps[3][m][nl];
    ctx[((size_t)b * NH + m) * DIM + c0 + nl] = r;
  }
}

extern "C" void kernel_launch(void* const* d_in, const int* in_sizes, int n_in,
                              void* d_out, int out_size, void* d_ws, size_t ws_size,
                              hipStream_t stream){
  const float* de   = (const float*)d_in[0];
  const float* enc  = (const float*)d_in[1];
  const float* pk   = (const float*)d_in[2];
  const float* pv   = (const float*)d_in[3];
  const int*   cl   = (const int*)d_in[4];
  const float* pe   = (const float*)d_in[5];
  const float* saqw = (const float*)d_in[6];
  const float* sakw = (const float*)d_in[7];
  const float* savw = (const float*)d_in[8];
  const float* saow = (const float*)d_in[9];
  const float* caqw = (const float*)d_in[10];
  const float* cakw = (const float*)d_in[11];
  const float* cavw = (const float*)d_in[12];
  const float* caow = (const float*)d_in[13];
  const float* saqb = (const float*)d_in[14];
  const float* sakb = (const float*)d_in[15];
  const float* savb = (const float*)d_in[16];
  const float* saob = (const float*)d_in[17];
  const float* caqb = (const float*)d_in[18];
  const float* cakb = (const float*)d_in[19];
  const float* cavb = (const float*)d_in[20];
  const float* caob = (const float*)d_in[21];
  const float* fc1w = (const float*)d_in[22];
  const float* fc1b = (const float*)d_in[23];
  const float* fc2w = (const float*)d_in[24];
  const float* fc2b = (const float*)d_in[25];
  const float* ln1w = (const float*)d_in[26];
  const float* ln2w = (const float*)d_in[27];
  const float* ln3w = (const float*)d_in[28];
  const float* ln1b = (const float*)d_in[29];
  const float* ln2b = (const float*)d_in[30];
  const float* ln3b = (const float*)d_in[31];
  const float* lmw  = (const float*)d_in[32];
  float* out = (float*)d_out;
  float* ws  = (float*)d_ws;

  int* flags   = (int*)ws;          // 16 slots, stride 32 ints
  float* h3buf = ws + 1024;         // [16][1024]
  float* h1buf = h3buf + 16384;     // [16][1024]
  float* h2buf = h1buf + 16384;     // [16][1024]
  float* satt  = h2buf + 16384;     // [16][1024]
  float* g     = satt + 16384;      // [16][16][1024]
  float* ctx   = g + 262144;        // [16][16][1024]
  float* Pqkv  = ctx + 262144;      // [3][4][16][1024]
  float* Po    = Pqkv + 196608;     // [8][16][1024]
  float* Pcq   = Po + 131072;       // [8][16][1024]
  float* Pvo   = Pcq + 131072;      // [8][16][1024]
  float* Pco   = Pvo + 131072;      // [8][16][1024]
  float* Pf1   = Pco + 131072;      // [4][16][4096]
  float* Pf2   = Pf1 + 262144;      // [32][16][1024]
  float* s2b   = Pf2 + 524288;      // [2][256][512]

  float* out_k = out + 512000;      // [L][16][1024]
  float* out_v = out + 610304;      // [L][16][1024]

  hipMemsetAsync(d_ws, 0, 2048, stream);   // zero flag slots (graph-safe)
  int gen = 0;

  for (int i = 0; i < LYRS; ++i){
    size_t wo = (size_t)i * DIM * DIM;
    size_t bo = (size_t)i * DIM;
    float* ko = out_k + (size_t)i * BD;
    float* vo = out_v + (size_t)i * BD;
    const float* pk_l = pk + (size_t)i * BATCH * NCACHE * DIM;
    const float* pv_l = pv + (size_t)i * BATCH * NCACHE * DIM;
    // ---- QKV (embed fused for i==0; ln3 of previous layer fused for i>=1) ----
    if (i == 0){
      k_qkv0<<<dim3(16, 3, 4), 256, 0, stream>>>(de, pe, cl,
          saqw + wo, sakw + wo, savw + wo, h3buf, Pqkv);
    } else {
      size_t po = (size_t)(i - 1) * DIM;
      k_gemv_lnf<256, 32><<<dim3(16, 3, 4), 256, 0, stream>>>(h2buf, Pf2, BD,
          fc2b + po, ln3w + po, ln3b + po,
          saqw + wo, sakw + wo, savw + wo, h3buf, flags, ++gen, Pqkv, DIM, BD);
    }
    // ---- self-attention ----
    k_self_attn<<<256, 512, 0, stream>>>(Pqkv, saqb + bo, sakb + bo, savb + bo,
        pk_l, pv_l, satt, ko, vo);
    // ---- O-projection -> Po slabs ----
    k_gemv_ms<128, 0, false><<<dim3(16, 1, 8), 256, 0, stream>>>(satt, DIM, 0,
        0, nullptr, saow + wo, DIM, 0, Po, DIM, 0, BD);
    // ---- cross-attn Q projection (ln1 fused in-kernel) ----
    k_gemv_lnf<128, 8><<<dim3(16, 1, 8), 256, 0, stream>>>(h3buf, Po, BD,
        saob + bo, ln1w + bo, ln1b + bo,
        caqw + wo, nullptr, nullptr, h1buf, flags, ++gen, Pcq, DIM, BD);
    // ---- g = qv . kw (K-projection folded into query) ----
    k_gmat2<<<dim3(16, 16), 256, 0, stream>>>(Pcq, caqb + bo, cakw + wo, g);
    // ---- scores ----
    k_gemv_ms<512, 0, false><<<dim3(8, 16, 2), 256, 0, stream>>>(g, DIM,
        NH * DIM, 0, nullptr, enc, DIM, SRCLEN * DIM, s2b, SRCLEN, NH * SRCLEN,
        BATCH * NH * SRCLEN);
    // ---- ctx with inline softmax ----
    k_ctx_sm<<<dim3(16, 16), 256, 0, stream>>>(s2b, enc, ctx);
    // ---- V-projection of ctx (per-head) ----
    k_gemv_ms<128, 0, false><<<dim3(1, 16, 8), 256, 0, stream>>>(ctx,
        NH * DIM, DIM, 0, nullptr, cavw + wo, DIM, HDIM * DIM, Pvo, DIM, HDIM, BD);
    // ---- cross-attn O-projection (folds Pvo + cavb) -> Pco slabs ----
    k_gemv_ms<128, 8, false><<<dim3(16, 1, 8), 256, 0, stream>>>(Pvo, DIM, 0,
        BD, cavb + bo, caow + wo, DIM, 0, Pco, DIM, 0, BD);
    // ---- fc1 (ln2 fused in-kernel) ----
    k_gemv_lnf<256, 8><<<dim3(64, 1, 4), 256, 0, stream>>>(h1buf, Pco, BD,
        caob + bo, ln2w + bo, ln2b + bo,
        fc1w + (size_t)i * FFNDIM * DIM, nullptr, nullptr,
        h2buf, flags, ++gen, Pf1, FFNDIM, BF);
    // ---- fc2 (folds 4 Pf1 slabs + fc1b + SiLU) -> Pf2 slabs ----
    k_gemv_ms<128, 4, true><<<dim3(16, 1, 32), 256, 0, stream>>>(Pf1, FFNDIM, 0,
        BF, fc1b + (size_t)i * FFNDIM,
        fc2w + (size_t)i * DIM * FFNDIM, FFNDIM, 0, Pf2, DIM, 0, BD);
  }
  // ---- final ln3 (standalone: lm grid is not co-residency-safe) ----
  {
    size_t po = (size_t)(LYRS - 1) * DIM;
    k_add_ln_pz<32><<<16, 256, 0, stream>>>(h2buf, Pf2, BD, fc2b + po,
        ln3w + po, ln3b + po, h3buf);
  }
  // ---- lm_head: single-pass, K=1024 in one block ----
  k_gemv_ms<1024, 0, false><<<dim3(VOCAB / 64, 1, 1), 256, 0, stream>>>(h3buf,
      DIM, 0, 0, nullptr, lmw, DIM, 0, out, VOCAB, 0, 0);
}